// Round 10
// baseline (32.690 us; speedup 1.0000x reference)
//
#include <hip/hip_runtime.h>
#include <hip/hip_bf16.h>

// VQ round 10: r7 structure, prep kernel eliminated.
//   score s_k = 4 + (-2z).e_k  (bf16 MFMA, swapped operands: C[code][zrow],
//   C-init = const {4,...}, D != C). The -2 is folded into the z staging:
//   bf16(-2x) == -2*bf16(x) exactly, so scores are bit-identical to r7.
//   key = (bits(s)&0xFFFFFC00) | code; uint-min = first-min.
//   E-fragments built in-kernel from emb (f32 -> cvt_pk_bf16, frag order) --
//   forces register residency (r7's 64-VGPR count proved the compiler was
//   re-reading ePack from L2 each ch-iter) and kills the vq_prep launch.
//   ||e||^2 for the loss is recomputed during the scatter gather (free bytes).
// vq_main: 512 blocks x 512 thr (8 waves; 128 rows/block; wave owns 128 codes).
// vq_loss2: deterministic pblk[512] reduce. No atomics, no fences.

typedef short short8v __attribute__((ext_vector_type(8)));
typedef float f32x4   __attribute__((ext_vector_type(4)));

__device__ __forceinline__ unsigned pk2(float a, float b) {
    __hip_bfloat162 h = __float22bfloat162_rn(make_float2(a, b));
    return *reinterpret_cast<unsigned*>(&h);
}
__device__ __forceinline__ unsigned umin2(unsigned a, unsigned b) { return a < b ? a : b; }

__global__ __launch_bounds__(512, 4)
void vq_main(const float* __restrict__ z,
             const float* __restrict__ emb,
             float* __restrict__ out,
             float* __restrict__ pblk) {
    // zA group G = sch*2 + half (16), lane (64), 8 bf16:
    //   (-2z)_bf16[row = sch*16 + (lane&15)][k = half*32 + (lane>>4)*8 + i]
    __shared__ short zA[16 * 64 * 8];      // 16 KB
    __shared__ float zsqp[4][128];
    __shared__ float esqp[4][128];
    __shared__ unsigned kbuf[8][128];
    __shared__ int bsel[128];
    __shared__ float red[2];

    const int tid  = threadIdx.x;
    const int lane = tid & 63;
    const int w    = tid >> 6;             // wave: owns codes [w*128, w*128+128)
    const int col  = lane & 15;
    const int kg   = lane >> 4;
    const int row0 = blockIdx.x << 7;

    // staging coords: row sr, channel-quarter q (16 channels each)
    const int sr   = tid & 127;
    const int q    = tid >> 7;
    const int sch  = sr >> 4;
    const int scol = sr & 15;
    const int n    = row0 + sr;
    const int zbase = ((n >> 12) << 18) + (n & 4095);   // b*64*4096 + hw

    // ---- phase 1a: issue z loads (staggered so LDS writes are 2-way) ----
    float zf[16];
    #pragma unroll
    for (int m = 0; m < 8; ++m) {
        const int skg = ((q & 1) << 1) | (m >> 2);
        const int ip  = ((m & 3) + sch) & 3;
        const int c   = ((q >> 1) << 5) + (skg << 3) + (ip << 1);
        zf[2 * m]     = z[zbase + (c << 12)];
        zf[2 * m + 1] = z[zbase + ((c + 1) << 12)];
    }

    // ---- phase 1b: E-frags (128 codes) built from emb; register-resident ----
    short8v b0[8], b1[8];
    {
        const float4* embv = (const float4*)emb;
        #pragma unroll
        for (int j = 0; j < 8; ++j) {
            const int code = (w << 7) + (j << 4) + col;
            const int rb = (code << 4) + (kg << 1);
            const float4 x0 = embv[rb];         // k = kg*8 .. +3
            const float4 x1 = embv[rb + 1];     // k = kg*8+4 .. +7
            const float4 x2 = embv[rb + 8];     // k = 32+kg*8 ..
            const float4 x3 = embv[rb + 9];
            union { short8v v; unsigned u[4]; } t;
            t.u[0] = pk2(x0.x, x0.y);
            t.u[1] = pk2(x0.z, x0.w);
            t.u[2] = pk2(x1.x, x1.y);
            t.u[3] = pk2(x1.z, x1.w);
            b0[j] = t.v;
            t.u[0] = pk2(x2.x, x2.y);
            t.u[1] = pk2(x2.z, x2.w);
            t.u[2] = pk2(x3.x, x3.y);
            t.u[3] = pk2(x3.z, x3.w);
            b1[j] = t.v;
        }
    }

    // ---- phase 1c: pack (-2z) -> zA + zsq partials (zsq from raw f32) ----
    {
        float ss = 0.0f;
        unsigned* zAu = (unsigned*)zA;
        #pragma unroll
        for (int m = 0; m < 8; ++m) {
            const int skg = ((q & 1) << 1) | (m >> 2);
            const int ip  = ((m & 3) + sch) & 3;
            const float f0 = zf[2 * m], f1 = zf[2 * m + 1];
            ss = fmaf(f1, f1, fmaf(f0, f0, ss));
            const int G = (sch << 1) + (q >> 1);
            zAu[((G << 6) + (skg << 4) + scol) * 4 + ip] = pk2(-2.0f * f0, -2.0f * f1);
        }
        zsqp[q][sr] = ss;
    }
    __syncthreads();

    // ---- K-loop: A = codes (regs), B = z-rows (LDS); argmin in-register ----
    const unsigned MASK = 0xFFFFFC00u;
    const f32x4 FOUR = {4.0f, 4.0f, 4.0f, 4.0f};
    const unsigned cbase = (unsigned)((w << 7) + (kg << 2));

    for (int ch = 0; ch < 8; ++ch) {
        const short8v zb0 = *(const short8v*)&zA[(((ch << 1) + 0) * 64 + lane) * 8];
        const short8v zb1 = *(const short8v*)&zA[(((ch << 1) + 1) * 64 + lane) * 8];
        unsigned best = 0xFFFFFFFFu;
        #pragma unroll
        for (int j = 0; j < 8; ++j) {
            f32x4 c = __builtin_amdgcn_mfma_f32_16x16x32_bf16(b1[j], zb1, FOUR, 0, 0, 0);
            c = __builtin_amdgcn_mfma_f32_16x16x32_bf16(b0[j], zb0, c, 0, 0, 0);
            const unsigned jb = cbase + (unsigned)(j << 4);
            const unsigned k0 = (__float_as_uint(c[0]) & MASK) | jb;
            const unsigned k1 = ((__float_as_uint(c[1]) & MASK) | jb) + 1u;
            const unsigned k2 = ((__float_as_uint(c[2]) & MASK) | jb) + 2u;
            const unsigned k3 = ((__float_as_uint(c[3]) & MASK) | jb) + 3u;
            best = umin2(best, umin2(umin2(k0, k1), umin2(k2, k3)));
        }
        best = umin2(best, (unsigned)__shfl_xor((int)best, 16));
        best = umin2(best, (unsigned)__shfl_xor((int)best, 32));
        if (kg == 0) kbuf[w][(ch << 4) + col] = best;   // zrow = ch*16+col
    }
    __syncthreads();

    // ---- cross-wave argmin (rows 0..127) ----
    unsigned kk = 0xFFFFFFFFu;
    if (tid < 128) {
        #pragma unroll
        for (int ww = 0; ww < 8; ++ww) kk = umin2(kk, kbuf[ww][tid]);
        bsel[tid] = (int)(kk & 1023u);
    }
    __syncthreads();

    // ---- gather chosen codes + scatter; fold ||e||^2 partials ----
    {
        const int code = bsel[sr];
        const float4* erow = (const float4*)emb + (code << 4) + (q << 2);
        float es = 0.0f;
        #pragma unroll
        for (int c4 = 0; c4 < 4; ++c4) {
            const float4 v = erow[c4];
            es = fmaf(v.x, v.x, es); es = fmaf(v.y, v.y, es);
            es = fmaf(v.z, v.z, es); es = fmaf(v.w, v.w, es);
            const int c = (q << 4) + (c4 << 2);
            out[zbase + ((c + 0) << 12)] = v.x;
            out[zbase + ((c + 1) << 12)] = v.y;
            out[zbase + ((c + 2) << 12)] = v.z;
            out[zbase + ((c + 3) << 12)] = v.w;
        }
        esqp[q][sr] = es;
    }
    __syncthreads();

    // ---- loss partial: d = ||z||^2 + (s_trunc - 4) + ||e||^2 ----
    if (tid < 128) {
        const float zs = (zsqp[0][tid] + zsqp[1][tid]) + (zsqp[2][tid] + zsqp[3][tid]);
        const float en = (esqp[0][tid] + esqp[1][tid]) + (esqp[2][tid] + esqp[3][tid]);
        float d = zs + __uint_as_float(kk & MASK) - 4.0f + en;
        #pragma unroll
        for (int m = 1; m < 64; m <<= 1) d += __shfl_xor(d, m);
        if (lane == 0) red[w] = d;
    }
    __syncthreads();
    if (tid == 0) pblk[blockIdx.x] = red[0] + red[1];
}

// Deterministic reduction of 512 per-block partials -> loss scalar.
__global__ void vq_loss2(const float* __restrict__ pblk,
                         float* __restrict__ out_loss) {
    const int tid = threadIdx.x;
    float d = pblk[tid] + pblk[tid + 256];
    #pragma unroll
    for (int m = 1; m < 64; m <<= 1) d += __shfl_xor(d, m);
    __shared__ float red[4];
    if ((tid & 63) == 0) red[tid >> 6] = d;
    __syncthreads();
    if (tid == 0)
        out_loss[0] = 1.25f * (red[0] + red[1] + red[2] + red[3]) * (1.0f / 4194304.0f);
}

extern "C" void kernel_launch(void* const* d_in, const int* in_sizes, int n_in,
                              void* d_out, int out_size, void* d_ws, size_t ws_size,
                              hipStream_t stream) {
    const float* z   = (const float*)d_in[0];
    const float* emb = (const float*)d_in[1];
    float* out  = (float*)d_out;
    float* pblk = (float*)d_ws;

    hipLaunchKernelGGL(vq_main, dim3(512), dim3(512), 0, stream, z, emb, out, pblk);
    hipLaunchKernelGGL(vq_loss2, dim3(1), dim3(256), 0, stream, pblk, out + 4194304);
}

// Round 12
// 25.952 us; speedup vs baseline: 1.2596x; 1.2596x over previous
//
#include <hip/hip_runtime.h>
#include <hip/hip_bf16.h>

// VQ round 12: r11 with the LDS-init bug fixed (r11's only real change).
//   r11 failure: the loss-partial shuffle-reduce + red[w] store were moved
//   inside `if (tid < 128)`, so red[2..7] were read uninitialized -> inf
//   after graph replays (stale LDS). Fix: all 8 waves reduce (d=0 for waves
//   2..7) and all 8 write red[w], exactly as round 7 did.
//   score s_k = 4 - 2 z.e_k  (bf16 MFMA, swapped operands: C[code][zrow],
//   C-init = const {4,...}, D != C). key = (bits(s)&0xFFFFFC00) | code;
//   uint-min = first-min. ||e||^2 (< key grain) re-added only in the loss.
// vq_prep: 256 blocks x 256 thr (wave = one code; 4 codes/block).
// vq_main: 512 blocks x 512 thr (8 waves; 4 waves/SIMD; wave owns 128 codes
//   in 64 VGPRs; A-frag z-tile staged once in 16 KB LDS; 3 barriers).
// vq_loss2: deterministic pblk[512] reduce. No atomics, no fences.

typedef short short8v __attribute__((ext_vector_type(8)));
typedef float f32x4   __attribute__((ext_vector_type(4)));

// ws byte offsets
#define OFF_EPACK 0        // 65536 shorts = 131072 B
#define OFF_ENORM 131072   // 1024 f32 (||e||^2 + 4)
#define OFF_PBLK  135168   // 512 f32

__device__ __forceinline__ unsigned short bf16r(float f) {
    unsigned u = __float_as_uint(f);
    return (unsigned short)((u + 0x7FFFu + ((u >> 16) & 1u)) >> 16);
}
__device__ __forceinline__ unsigned pk2(float a, float b) {
    __hip_bfloat162 h = __float22bfloat162_rn(make_float2(a, b));
    return *reinterpret_cast<unsigned*>(&h);
}
__device__ __forceinline__ unsigned umin2(unsigned a, unsigned b) { return a < b ? a : b; }

// 256 blocks x 256 threads; wave handles one code (4 codes/block).
// ePack[((t*2+s)*64 + (kg<<4|col))*8 + i] = bf16(-2*emb[t*16+col][s*32+kg*8+i])
__global__ void vq_prep(const float* __restrict__ emb,
                        short* __restrict__ ePack,
                        float* __restrict__ enormP4) {
    const int code = (blockIdx.x << 2) + (threadIdx.x >> 6);
    const int k = threadIdx.x & 63;
    const float v = emb[(code << 6) + k];
    float s = v * v;
    #pragma unroll
    for (int o = 32; o > 0; o >>= 1) s += __shfl_down(s, o);
    if (k == 0) enormP4[code] = s + 4.0f;
    const int t   = code >> 4;
    const int s32 = k >> 5;
    const int l   = (((k >> 3) & 3) << 4) | (code & 15);
    const int i   = k & 7;
    ePack[(((t * 2 + s32) * 64) + l) * 8 + i] = (short)bf16r(-2.0f * v);
}

__global__ __launch_bounds__(512, 4)
void vq_main(const float* __restrict__ z,
             const short* __restrict__ ePack,
             const float* __restrict__ enormP4,
             const float* __restrict__ emb,
             float* __restrict__ out,
             float* __restrict__ pblk) {
    // zA group G = sch*2 + half (16), lane (64), 8 bf16:
    //   z_bf16[row = sch*16 + (lane&15)][k = half*32 + (lane>>4)*8 + i]
    __shared__ short zA[16 * 64 * 8];      // 16 KB
    __shared__ float zsqp[4][128];
    __shared__ unsigned kbuf[8][128];
    __shared__ int bsel[128];
    __shared__ float red[8];

    const int tid  = threadIdx.x;
    const int lane = tid & 63;
    const int w    = tid >> 6;             // wave: owns codes [w*128, w*128+128)
    const int col  = lane & 15;
    const int kg   = lane >> 4;
    const int row0 = blockIdx.x << 7;

    // staging coords: row sr, channel-quarter q (16 channels each)
    const int sr   = tid & 127;
    const int q    = tid >> 7;
    const int sch  = sr >> 4;
    const int scol = sr & 15;
    const int n    = row0 + sr;
    const int zbase = ((n >> 12) << 18) + (n & 4095);   // b*64*4096 + hw

    // ---- phase 1a: issue z loads (staggered so LDS writes are 2-way) ----
    float zf[16];
    #pragma unroll
    for (int m = 0; m < 8; ++m) {
        const int skg = ((q & 1) << 1) | (m >> 2);
        const int ip  = ((m & 3) + sch) & 3;
        const int c   = ((q >> 1) << 5) + (skg << 3) + (ip << 1);
        zf[2 * m]     = z[zbase + (c << 12)];
        zf[2 * m + 1] = z[zbase + ((c + 1) << 12)];
    }

    // ---- phase 1b: E-frags (128 codes) into 64 VGPRs; L2-hot ----
    short8v b0[8], b1[8];
    #pragma unroll
    for (int j = 0; j < 8; ++j) {
        const int t = (w << 3) + j;
        b0[j] = *(const short8v*)(ePack + ((t * 2 + 0) * 64 + lane) * 8);
        b1[j] = *(const short8v*)(ePack + ((t * 2 + 1) * 64 + lane) * 8);
    }

    // ---- phase 1c: pack z -> zA + zsq partials ----
    {
        float ss = 0.0f;
        unsigned* zAu = (unsigned*)zA;
        #pragma unroll
        for (int m = 0; m < 8; ++m) {
            const int skg = ((q & 1) << 1) | (m >> 2);
            const int ip  = ((m & 3) + sch) & 3;
            const float f0 = zf[2 * m], f1 = zf[2 * m + 1];
            ss = fmaf(f1, f1, fmaf(f0, f0, ss));
            const int G = (sch << 1) + (q >> 1);
            zAu[((G << 6) + (skg << 4) + scol) * 4 + ip] = pk2(f0, f1);
        }
        zsqp[q][sr] = ss;
    }
    __syncthreads();

    // ---- K-loop: A = codes (regs), B = z-rows (LDS); argmin in-register ----
    const unsigned MASK = 0xFFFFFC00u;
    const f32x4 FOUR = {4.0f, 4.0f, 4.0f, 4.0f};
    const unsigned cbase = (unsigned)((w << 7) + (kg << 2));

    for (int ch = 0; ch < 8; ++ch) {
        const short8v zb0 = *(const short8v*)&zA[(((ch << 1) + 0) * 64 + lane) * 8];
        const short8v zb1 = *(const short8v*)&zA[(((ch << 1) + 1) * 64 + lane) * 8];
        unsigned best = 0xFFFFFFFFu;
        #pragma unroll
        for (int j = 0; j < 8; ++j) {
            f32x4 c = __builtin_amdgcn_mfma_f32_16x16x32_bf16(b1[j], zb1, FOUR, 0, 0, 0);
            c = __builtin_amdgcn_mfma_f32_16x16x32_bf16(b0[j], zb0, c, 0, 0, 0);
            const unsigned jb = cbase + (unsigned)(j << 4);
            const unsigned k0 = (__float_as_uint(c[0]) & MASK) | jb;
            const unsigned k1 = ((__float_as_uint(c[1]) & MASK) | jb) + 1u;
            const unsigned k2 = ((__float_as_uint(c[2]) & MASK) | jb) + 2u;
            const unsigned k3 = ((__float_as_uint(c[3]) & MASK) | jb) + 3u;
            best = umin2(best, umin2(umin2(k0, k1), umin2(k2, k3)));
        }
        best = umin2(best, (unsigned)__shfl_xor((int)best, 16));
        best = umin2(best, (unsigned)__shfl_xor((int)best, 32));
        if (kg == 0) kbuf[w][(ch << 4) + col] = best;   // zrow = ch*16+col
    }
    __syncthreads();

    // ---- cross-wave argmin + exact loss partial (ALL waves reduce; r7) ----
    float d = 0.0f;
    if (tid < 128) {
        unsigned kk = 0xFFFFFFFFu;
        #pragma unroll
        for (int ww = 0; ww < 8; ++ww) kk = umin2(kk, kbuf[ww][tid]);
        const int code = (int)(kk & 1023u);
        bsel[tid] = code;
        // d = ||z||^2 + (s_trunc - 4) + (enormP4[code] - 4)
        d = zsqp[0][tid] + zsqp[1][tid] + zsqp[2][tid] + zsqp[3][tid]
            + __uint_as_float(kk & MASK) + enormP4[code] - 8.0f;
    }
    #pragma unroll
    for (int m = 1; m < 64; m <<= 1) d += __shfl_xor(d, m);
    if (lane == 0) red[w] = d;           // ALL 8 waves write red[w]
    __syncthreads();
    if (tid == 0)
        pblk[blockIdx.x] = ((red[0] + red[1]) + (red[2] + red[3]))
                         + ((red[4] + red[5]) + (red[6] + red[7]));

    // ---- gather chosen codes + scatter to channel-major output ----
    {
        const int code = bsel[sr];
        const float4* erow = (const float4*)emb + (code << 4) + (q << 2);
        #pragma unroll
        for (int c4 = 0; c4 < 4; ++c4) {
            const float4 v = erow[c4];
            const int c = (q << 4) + (c4 << 2);
            out[zbase + ((c + 0) << 12)] = v.x;
            out[zbase + ((c + 1) << 12)] = v.y;
            out[zbase + ((c + 2) << 12)] = v.z;
            out[zbase + ((c + 3) << 12)] = v.w;
        }
    }
}

// Deterministic reduction of 512 per-block partials -> loss scalar.
__global__ void vq_loss2(const float* __restrict__ pblk,
                         float* __restrict__ out_loss) {
    const int tid = threadIdx.x;
    float d = pblk[tid] + pblk[tid + 256];
    #pragma unroll
    for (int m = 1; m < 64; m <<= 1) d += __shfl_xor(d, m);
    __shared__ float red[4];
    if ((tid & 63) == 0) red[tid >> 6] = d;
    __syncthreads();
    if (tid == 0)
        out_loss[0] = 1.25f * (red[0] + red[1] + red[2] + red[3]) * (1.0f / 4194304.0f);
}

extern "C" void kernel_launch(void* const* d_in, const int* in_sizes, int n_in,
                              void* d_out, int out_size, void* d_ws, size_t ws_size,
                              hipStream_t stream) {
    const float* z   = (const float*)d_in[0];
    const float* emb = (const float*)d_in[1];
    float* out = (float*)d_out;
    char*  ws  = (char*)d_ws;

    short* ePack   = (short*)(ws + OFF_EPACK);
    float* enormP4 = (float*)(ws + OFF_ENORM);
    float* pblk    = (float*)(ws + OFF_PBLK);

    hipLaunchKernelGGL(vq_prep, dim3(256), dim3(256), 0, stream, emb, ePack, enormP4);
    hipLaunchKernelGGL(vq_main, dim3(512), dim3(512), 0, stream,
                       z, ePack, enormP4, emb, out, pblk);
    hipLaunchKernelGGL(vq_loss2, dim3(1), dim3(256), 0, stream, pblk, out + 4194304);
}